// Round 8
// baseline (131.251 us; speedup 1.0000x reference)
//
#include <hip/hip_runtime.h>
#include <math.h>

#define BB 64
#define AA 8732
#define DD 85
#define GG 32
#define CC 81
#define TILE 64
#define NT 137        /* ceil(8732/64) tiles */
#define TPB 12        /* tiles per k_loss block */
#define NTB 12        /* k_loss grid.x ; 768 blocks = 3/CU resident */
#define NAB 35        /* ceil(8732/256) stage-A blocks in k_match */
#define BLKANCH (TPB * TILE)   /* 768 anchors per k_loss block */

// ---------------- workspace layout (bytes) ----------------
// match:       0        .. 2235392   (B*A int32)
// all_neg:     2235392  .. 4470784   (B*A float)
// partials:    4470784  .. 4473856   (B*NTB float)
// batch_total: 4473856  .. 4474112   (B float)
// bestp:       4474112  .. 4482304   (B*G int32)
// n_pos:       4482304  .. 4482560   (B int32)   } zeroed by k_match blk(0,b)
// done_l:      4482560  .. 4482816   (B int32)   } (safe: only k_loss uses)
// done_sel:    4482816  .. 4482820   (int32)     }

typedef __attribute__((address_space(3))) unsigned int lds_u32;
typedef const __attribute__((address_space(1))) unsigned int glb_u32;

__device__ __forceinline__ float smoothl1(float d) {
  float ad = fabsf(d);
  return ad < 1.0f ? 0.5f * d * d : ad - 0.5f;
}

__device__ __forceinline__ float frcp(float x) {
  return __builtin_amdgcn_rcpf(x);
}

// Fused matcher. grid (NAB+GG, B), 256 threads.
//  blocks [0,NAB):   stage A — per-anchor best GT (threshold), first-max-wins
//  blocks [NAB,+GG): stage B — per-GT best anchor (forced match argmax)
// block (0,b) zeroes the k_loss counters (k_loss launches strictly after).
__global__ __launch_bounds__(256) void k_match(
    const float* __restrict__ anchors, const float* __restrict__ gt_boxes,
    const int* __restrict__ gt_counts, int* __restrict__ match,
    int* __restrict__ bestp, int* __restrict__ n_pos,
    int* __restrict__ done_l, int* __restrict__ done_sel)
{
  const int b = blockIdx.y;
  const int count = gt_counts[b];
  __shared__ float gx0[GG], gy0[GG], gx1[GG], gy1[GG], gar[GG];
  __shared__ float wv[4];
  __shared__ int wi[4];

  if (blockIdx.x < NAB) {
    if (blockIdx.x == 0 && threadIdx.x == 0) {
      n_pos[b] = 0;
      done_l[b] = 0;
      if (b == 0) *done_sel = 0;
    }
    if (threadIdx.x < GG) {
      float4 gb = reinterpret_cast<const float4*>(gt_boxes)[b * GG + threadIdx.x];
      float x0 = gb.x - gb.z * 0.5f, y0 = gb.y - gb.w * 0.5f;
      float x1 = gb.x + gb.z * 0.5f, y1 = gb.y + gb.w * 0.5f;
      gx0[threadIdx.x] = x0; gy0[threadIdx.x] = y0;
      gx1[threadIdx.x] = x1; gy1[threadIdx.x] = y1;
      gar[threadIdx.x] = (x1 - x0) * (y1 - y0);
    }
    __syncthreads();
    const int a = blockIdx.x * 256 + threadIdx.x;
    if (a < AA) {
      float4 an = reinterpret_cast<const float4*>(anchors)[a];
      float ax0 = an.x - an.z * 0.5f, ay0 = an.y - an.w * 0.5f;
      float ax1 = an.x + an.z * 0.5f, ay1 = an.y + an.w * 0.5f;
      float aar = (ax1 - ax0) * (ay1 - ay0);
      float best = -1.0f; int bi = 0;
      for (int g = 0; g < count; ++g) {
        float iw = fmaxf(fminf(gx1[g], ax1) - fmaxf(gx0[g], ax0), 0.0f);
        float ih = fmaxf(fminf(gy1[g], ay1) - fmaxf(gy0[g], ay0), 0.0f);
        float inter = iw * ih;
        float iou = inter * frcp(gar[g] + aar - inter);
        if (iou > best) { best = iou; bi = g; }   // first max wins
      }
      match[b * AA + a] = (best > 0.5f) ? bi : -1;
    }
  } else {
    const int g = blockIdx.x - NAB;
    if (g < count) {
      float4 gb = reinterpret_cast<const float4*>(gt_boxes)[b * GG + g];
      const float gx0s = gb.x - gb.z * 0.5f, gy0s = gb.y - gb.w * 0.5f;
      const float gx1s = gb.x + gb.z * 0.5f, gy1s = gb.y + gb.w * 0.5f;
      const float gars = (gx1s - gx0s) * (gy1s - gy0s);

      float bv = -2.0f; int bi = AA;
      for (int a = threadIdx.x; a < AA; a += 256) {
        float4 an = reinterpret_cast<const float4*>(anchors)[a];
        float ax0 = an.x - an.z * 0.5f, ay0 = an.y - an.w * 0.5f;
        float ax1 = an.x + an.z * 0.5f, ay1 = an.y + an.w * 0.5f;
        float aar = (ax1 - ax0) * (ay1 - ay0);
        float iw = fmaxf(fminf(gx1s, ax1) - fmaxf(gx0s, ax0), 0.0f);
        float ih = fmaxf(fminf(gy1s, ay1) - fmaxf(gy0s, ay0), 0.0f);
        float inter = iw * ih;
        float iou = inter * frcp(gars + aar - inter);
        if (iou > bv || (iou == bv && a < bi)) { bv = iou; bi = a; }
      }
      #pragma unroll
      for (int m = 1; m < 64; m <<= 1) {
        float ov = __shfl_xor(bv, m);
        int   oi = __shfl_xor(bi, m);
        if (ov > bv || (ov == bv && oi < bi)) { bv = ov; bi = oi; }
      }
      if ((threadIdx.x & 63) == 0) { wv[threadIdx.x >> 6] = bv; wi[threadIdx.x >> 6] = bi; }
      __syncthreads();
      if (threadIdx.x == 0) {
        float fv = wv[0]; int fi = wi[0];
        #pragma unroll
        for (int w = 1; w < 4; ++w)
          if (wv[w] > fv || (wv[w] == fv && wi[w] < fi)) { fv = wv[w]; fi = wi[w]; }
        bestp[b * GG + g] = fi;
      }
    }
  }
}

// Mega-kernel: grid (NTB, B), 256 threads.
// Loss phase (12 tiles, dbuf LDS + global_load_lds prefetch) with per-block
// forced-match override table; then the LAST block of each batch runs the
// radix top-K select inline (LDS reused), and the last select block writes out.
__global__ __launch_bounds__(256) void k_loss(
    const float* __restrict__ pred, const float* __restrict__ anchors,
    const float* __restrict__ gt_boxes, const int* __restrict__ gt_labels,
    const int* __restrict__ gt_counts, const int* __restrict__ match,
    const int* __restrict__ bestp, float* __restrict__ all_neg,
    float* __restrict__ partials, int* __restrict__ n_pos,
    int* __restrict__ done_l, int* __restrict__ done_sel,
    float* __restrict__ batch_total, float* __restrict__ out)
{
  const int b = blockIdx.y;
  const int t0 = blockIdx.x * TPB;
  const int t1 = min(t0 + TPB, NT);
  const int abase = t0 * TILE;
  const int tid = threadIdx.x;
  __shared__ float bufs[2][TILE * DD];   // 43520 B (reused by select phase)
  __shared__ int ovrblk[BLKANCH];        // 3072 B
  __shared__ int slab[GG];
  __shared__ float wsum[4];
  __shared__ int wcnt[4];
  __shared__ int sflag;
  __shared__ unsigned sh_pref;
  __shared__ int sh_k;

  if (tid < GG) slab[tid] = gt_labels[b * GG + tid];
  for (int i = tid; i < BLKANCH; i += 256) ovrblk[i] = -1;

  #define PREFETCH(t, bufp)                                                  \
    do {                                                                     \
      const int a0_ = (t) * TILE;                                            \
      const int nch_ = (min(TILE, AA - a0_) * DD) >> 2;                      \
      const float* s_ = pred + ((size_t)b * AA + a0_) * DD;                  \
      _Pragma("unroll")                                                      \
      for (int j_ = 0; j_ < 6; ++j_) {                                       \
        int c_ = j_ * 256 + tid;                                             \
        if (c_ < nch_)                                                       \
          __builtin_amdgcn_global_load_lds(                                  \
              (glb_u32*)(s_ + c_ * 4), (lds_u32*)((bufp) + c_ * 4), 16, 0, 0);\
      }                                                                      \
    } while (0)

  PREFETCH(t0, &bufs[0][0]);
  __syncthreads();   // slab/ovrblk-init visible; prologue tile resident

  // forced-match override scatter (max g == ascending last-write-wins)
  if (tid < GG && tid < gt_counts[b]) {
    int p = bestp[b * GG + tid];
    if (p >= abase && p < abase + BLKANCH) atomicMax(&ovrblk[p - abase], tid);
  }
  __syncthreads();

  const int r = tid >> 2;
  const int sub = tid & 3;
  float acc = 0.0f;
  int poscnt = 0;
  int cur = 0;

  for (int t = t0; t < t1; ++t) {
    if (t + 1 < t1) {
      PREFETCH(t + 1, &bufs[cur ^ 1][0]);
      __builtin_amdgcn_sched_barrier(0);   // keep issue ahead of compute
    }

    const int a0 = t * TILE;
    const int nr = min(TILE, AA - a0);
    const float* rows = &bufs[cur][0];

    if (r < nr) {
      const int a = a0 + r;
      int m = match[b * AA + a];
      { int o = ovrblk[a - abase]; if (o >= 0) m = o; }

      const float* row = rows + r * DD + 4;
      float v[21];
      float mx = -INFINITY;
      #pragma unroll
      for (int k = 0; k < 21; ++k) {
        const int cc = 4 * k + sub;
        float x = (cc < CC) ? row[cc] : -INFINITY;
        v[k] = x;
        mx = fmaxf(mx, x);
      }
      #pragma unroll
      for (int msk = 1; msk <= 2; msk <<= 1)
        mx = fmaxf(mx, __shfl_xor(mx, msk));
      float s = 0.0f;
      #pragma unroll
      for (int k = 0; k < 21; ++k) s += __expf(v[k] - mx);  // exp(-inf)=0 pads
      #pragma unroll
      for (int msk = 1; msk <= 2; msk <<= 1) s += __shfl_xor(s, msk);
      const float lse = mx + __logf(s);

      if (sub == 0) {
        if (m >= 0) {
          poscnt += 1;
          const int tgt = slab[m] + 1;
          float cls_ce = lse - row[tgt];
          float4 an = reinterpret_cast<const float4*>(anchors)[a];
          float4 gb = reinterpret_cast<const float4*>(gt_boxes)[b * GG + m];
          float tx = (gb.x - an.x) / an.z;
          float ty = (gb.y - an.y) / an.w;
          float tw = __logf(gb.z) - __logf(an.z);
          float th = __logf(gb.w) - __logf(an.w);
          acc += smoothl1(rows[r * DD + 0] - tx)
               + smoothl1(rows[r * DD + 1] - ty)
               + smoothl1(rows[r * DD + 2] - tw)
               + smoothl1(rows[r * DD + 3] - th)
               + cls_ce;
          all_neg[b * AA + a] = 0.0f;
        } else {
          float ce = lse - row[0];          // tgt==0 for negatives
          all_neg[b * AA + a] = fmaxf(ce, 0.0f);
        }
      }
    }

    __syncthreads();   // reads done + prefetch drained (vmcnt covers stores too)
    cur ^= 1;
  }

  #pragma unroll
  for (int msk = 1; msk < 64; msk <<= 1) {
    acc    += __shfl_xor(acc, msk);
    poscnt += __shfl_xor(poscnt, msk);
  }
  if ((tid & 63) == 0) {
    wsum[tid >> 6] = acc;
    wcnt[tid >> 6] = poscnt;
  }
  __syncthreads();
  if (tid == 0) {
    partials[b * NTB + blockIdx.x] = (wsum[0] + wsum[1]) + (wsum[2] + wsum[3]);
    int c = wcnt[0] + wcnt[1] + wcnt[2] + wcnt[3];
    if (c) atomicAdd(&n_pos[b], c);        // integer add: order-independent
    __threadfence();                        // release: stores -> device scope
    int old = atomicAdd(&done_l[b], 1);
    sflag = (old == NTB - 1) ? 1 : 0;
  }
  __syncthreads();

  // ======== select phase: only the last block of batch b ========
  if (sflag) {
    __threadfence();                        // acquire: invalidate caches
    char* sbase = (char*)&bufs[0][0];       // reuse the 43.5KB tile buffer
    unsigned* u = (unsigned*)sbase;         // [0, 34928)
    int* hist4  = (int*)(sbase + 34944);    // 4*257 ints -> 39056
    int* hist   = (int*)(sbase + 39056);    // 256 ints  -> 40080
    int* gsum   = (int*)(sbase + 40080);    // 64 ints   -> 40336

    const float* srcg = all_neg + (size_t)b * AA;   // 16B-aligned, /4 exact
    #pragma unroll
    for (int j = 0; j < 9; ++j) {
      int c = j * 256 + tid;
      if (c < 2183)
        __builtin_amdgcn_global_load_lds(
            (glb_u32*)(srcg + c * 4), (lds_u32*)((float*)u + c * 4), 16, 0, 0);
    }
    __syncthreads();

    const int np = n_pos[b];
    const int K = min(3 * np, AA - 1);
    const int wvid = tid >> 6;

    unsigned prefix = 0;
    int kk = K;
    for (int shift = 24; shift >= 0; shift -= 8) {
      for (int i = tid; i < 4 * 257; i += 256) hist4[i] = 0;
      __syncthreads();
      const unsigned hmask = (shift == 24) ? 0u : (0xFFFFFFFFu << (shift + 8));
      for (int i = tid; i < AA; i += 256) {
        unsigned x = u[i];
        if ((x & hmask) == prefix)
          atomicAdd(&hist4[wvid * 257 + ((x >> shift) & 255)], 1);
      }
      __syncthreads();
      {
        int s = hist4[tid] + hist4[257 + tid] + hist4[514 + tid] + hist4[771 + tid];
        hist[tid] = s;
      }
      __syncthreads();
      if (tid < 64) {
        int base = 255 - 4 * tid;
        gsum[tid] = hist[base] + hist[base - 1] + hist[base - 2] + hist[base - 3];
      }
      __syncthreads();
      if (tid == 0) {
        int cum = 0, chosen = 0;
        const int kv = kk;
        for (int t = 0; t < 64; ++t) {
          int gs = gsum[t];
          if (cum + gs < kv) { cum += gs; continue; }
          for (int bin = 255 - 4 * t; bin >= 252 - 4 * t; --bin) {
            int h = hist[bin];
            if (cum + h >= kv) { chosen = bin; break; }
            cum += h;
          }
          break;
        }
        sh_pref = prefix | ((unsigned)chosen << shift);
        sh_k = kk - cum;
      }
      __syncthreads();
      prefix = sh_pref;
      kk = sh_k;
      __syncthreads();
    }
    const float tstar = __uint_as_float(prefix);   // exact K-th largest

    float ssum = 0.0f; int cgt = 0;
    for (int i = tid; i < AA; i += 256) {
      float x = __uint_as_float(u[i]);
      if (x > tstar) { ssum += x; cgt += 1; }
    }
    #pragma unroll
    for (int m = 1; m < 64; m <<= 1) {
      ssum += __shfl_xor(ssum, m);
      cgt  += __shfl_xor(cgt, m);
    }
    if ((tid & 63) == 0) { wsum[wvid] = ssum; wcnt[wvid] = cgt; }
    __syncthreads();
    if (tid == 0) {
      float S = (wsum[0] + wsum[1]) + (wsum[2] + wsum[3]);
      int Cg = wcnt[0] + wcnt[1] + wcnt[2] + wcnt[3];
      float neg_sum = S + (float)(K - Cg) * tstar;
      float ps = 0.0f;
      for (int t = 0; t < NTB; ++t) ps += partials[b * NTB + t];
      batch_total[b] = (ps + neg_sum) / (float)np;
      __threadfence();                      // release batch_total
      int old = atomicAdd(done_sel, 1);
      if (old == BB - 1) {                  // global last: final sum, fixed order
        __threadfence();
        float s = 0.0f;
        for (int bb = 0; bb < BB; ++bb) s += batch_total[bb];
        out[0] = s;
      }
    }
  }
  #undef PREFETCH
}

extern "C" void kernel_launch(void* const* d_in, const int* in_sizes, int n_in,
                              void* d_out, int out_size, void* d_ws, size_t ws_size,
                              hipStream_t stream) {
  (void)in_sizes; (void)n_in; (void)out_size; (void)ws_size;
  const float* pred      = (const float*)d_in[0];
  const float* anchors   = (const float*)d_in[1];
  const float* gt_boxes  = (const float*)d_in[2];
  const int*   gt_labels = (const int*)d_in[3];
  const int*   gt_counts = (const int*)d_in[4];

  char* ws = (char*)d_ws;
  int*   match       = (int*)(ws + 0);
  float* all_neg     = (float*)(ws + 2235392);
  float* partials    = (float*)(ws + 4470784);
  float* batch_total = (float*)(ws + 4473856);
  int*   bestp       = (int*)(ws + 4474112);
  int*   n_pos       = (int*)(ws + 4482304);
  int*   done_l      = (int*)(ws + 4482560);
  int*   done_sel    = (int*)(ws + 4482816);
  float* out = (float*)d_out;

  hipLaunchKernelGGL(k_match, dim3(NAB + GG, BB), dim3(256), 0, stream,
                     anchors, gt_boxes, gt_counts, match, bestp,
                     n_pos, done_l, done_sel);
  hipLaunchKernelGGL(k_loss, dim3(NTB, BB), dim3(256), 0, stream,
                     pred, anchors, gt_boxes, gt_labels, gt_counts, match, bestp,
                     all_neg, partials, n_pos, done_l, done_sel,
                     batch_total, out);
}

// Round 9
// 88.038 us; speedup vs baseline: 1.4908x; 1.4908x over previous
//
#include <hip/hip_runtime.h>
#include <math.h>

#define BB 64
#define AA 8732
#define DD 85
#define GG 32
#define CC 81
#define TILE 64
#define NT 137        /* ceil(8732/64) tiles */
#define TPB 12        /* tiles per k_loss block */
#define NTB 12        /* k_loss grid.x ; 768 blocks = 3/CU resident */
#define NAB 35        /* ceil(8732/256) stage-A blocks in k_match */
#define BLKANCH (TPB * TILE)   /* 768 anchors per k_loss block */

// ---------------- workspace layout (bytes) ----------------
// match:       0        .. 2235392   (B*A int32)
// all_neg:     2235392  .. 4470784   (B*A float)
// partials:    4470784  .. 4473856   (B*NTB float)
// batch_total: 4473856  .. 4474112   (B float)
// bestp:       4474112  .. 4482304   (B*G int32)
// n_pos:       4482304  .. 4482560   (B int32)   } zeroed by k_match blk(0,b)
// done_sel:    4482560  .. 4482564   (int32)     } (safe: used 2 kernels later)

typedef __attribute__((address_space(3))) unsigned int lds_u32;
typedef const __attribute__((address_space(1))) unsigned int glb_u32;

__device__ __forceinline__ float smoothl1(float d) {
  float ad = fabsf(d);
  return ad < 1.0f ? 0.5f * d * d : ad - 0.5f;
}

__device__ __forceinline__ float frcp(float x) {
  return __builtin_amdgcn_rcpf(x);
}

// Fused matcher. grid (NAB+GG, B), 256 threads.
//  blocks [0,NAB):   stage A — per-anchor best GT (threshold), first-max-wins
//  blocks [NAB,+GG): stage B — per-GT best anchor (forced match argmax)
__global__ __launch_bounds__(256) void k_match(
    const float* __restrict__ anchors, const float* __restrict__ gt_boxes,
    const int* __restrict__ gt_counts, int* __restrict__ match,
    int* __restrict__ bestp, int* __restrict__ n_pos, int* __restrict__ done_sel)
{
  const int b = blockIdx.y;
  const int count = gt_counts[b];
  __shared__ float gx0[GG], gy0[GG], gx1[GG], gy1[GG], gar[GG];
  __shared__ float wv[4];
  __shared__ int wi[4];

  if (blockIdx.x < NAB) {
    if (blockIdx.x == 0 && threadIdx.x == 0) {
      n_pos[b] = 0;
      if (b == 0) *done_sel = 0;
    }
    if (threadIdx.x < GG) {
      float4 gb = reinterpret_cast<const float4*>(gt_boxes)[b * GG + threadIdx.x];
      float x0 = gb.x - gb.z * 0.5f, y0 = gb.y - gb.w * 0.5f;
      float x1 = gb.x + gb.z * 0.5f, y1 = gb.y + gb.w * 0.5f;
      gx0[threadIdx.x] = x0; gy0[threadIdx.x] = y0;
      gx1[threadIdx.x] = x1; gy1[threadIdx.x] = y1;
      gar[threadIdx.x] = (x1 - x0) * (y1 - y0);
    }
    __syncthreads();
    const int a = blockIdx.x * 256 + threadIdx.x;
    if (a < AA) {
      float4 an = reinterpret_cast<const float4*>(anchors)[a];
      float ax0 = an.x - an.z * 0.5f, ay0 = an.y - an.w * 0.5f;
      float ax1 = an.x + an.z * 0.5f, ay1 = an.y + an.w * 0.5f;
      float aar = (ax1 - ax0) * (ay1 - ay0);
      float best = -1.0f; int bi = 0;
      for (int g = 0; g < count; ++g) {
        float iw = fmaxf(fminf(gx1[g], ax1) - fmaxf(gx0[g], ax0), 0.0f);
        float ih = fmaxf(fminf(gy1[g], ay1) - fmaxf(gy0[g], ay0), 0.0f);
        float inter = iw * ih;
        float iou = inter * frcp(gar[g] + aar - inter);
        if (iou > best) { best = iou; bi = g; }   // first max wins
      }
      match[b * AA + a] = (best > 0.5f) ? bi : -1;
    }
  } else {
    const int g = blockIdx.x - NAB;
    if (g < count) {
      float4 gb = reinterpret_cast<const float4*>(gt_boxes)[b * GG + g];
      const float gx0s = gb.x - gb.z * 0.5f, gy0s = gb.y - gb.w * 0.5f;
      const float gx1s = gb.x + gb.z * 0.5f, gy1s = gb.y + gb.w * 0.5f;
      const float gars = (gx1s - gx0s) * (gy1s - gy0s);

      float bv = -2.0f; int bi = AA;
      for (int a = threadIdx.x; a < AA; a += 256) {
        float4 an = reinterpret_cast<const float4*>(anchors)[a];
        float ax0 = an.x - an.z * 0.5f, ay0 = an.y - an.w * 0.5f;
        float ax1 = an.x + an.z * 0.5f, ay1 = an.y + an.w * 0.5f;
        float aar = (ax1 - ax0) * (ay1 - ay0);
        float iw = fmaxf(fminf(gx1s, ax1) - fmaxf(gx0s, ax0), 0.0f);
        float ih = fmaxf(fminf(gy1s, ay1) - fmaxf(gy0s, ay0), 0.0f);
        float inter = iw * ih;
        float iou = inter * frcp(gars + aar - inter);
        if (iou > bv || (iou == bv && a < bi)) { bv = iou; bi = a; }
      }
      #pragma unroll
      for (int m = 1; m < 64; m <<= 1) {
        float ov = __shfl_xor(bv, m);
        int   oi = __shfl_xor(bi, m);
        if (ov > bv || (ov == bv && oi < bi)) { bv = ov; bi = oi; }
      }
      if ((threadIdx.x & 63) == 0) { wv[threadIdx.x >> 6] = bv; wi[threadIdx.x >> 6] = bi; }
      __syncthreads();
      if (threadIdx.x == 0) {
        float fv = wv[0]; int fi = wi[0];
        #pragma unroll
        for (int w = 1; w < 4; ++w)
          if (wv[w] > fv || (wv[w] == fv && wi[w] < fi)) { fv = wv[w]; fi = wi[w]; }
        bestp[b * GG + g] = fi;
      }
    }
  }
}

// Heavy pass (R7 core): grid (NTB, B), 256 threads, 4 threads/row.
// Double-buffered LDS + global_load_lds prefetch; per-block ovrblk override
// table replaces the k_scatter launch. No fences anywhere.
__global__ __launch_bounds__(256) void k_loss(
    const float* __restrict__ pred, const float* __restrict__ anchors,
    const float* __restrict__ gt_boxes, const int* __restrict__ gt_labels,
    const int* __restrict__ gt_counts, const int* __restrict__ match,
    const int* __restrict__ bestp, float* __restrict__ all_neg,
    float* __restrict__ partials, int* __restrict__ n_pos)
{
  const int b = blockIdx.y;
  const int t0 = blockIdx.x * TPB;
  const int t1 = min(t0 + TPB, NT);
  const int abase = t0 * TILE;
  const int tid = threadIdx.x;
  __shared__ float bufs[2][TILE * DD];   // 43520 B
  __shared__ int ovrblk[BLKANCH];        // 3072 B
  __shared__ int slab[GG];
  __shared__ float wsum[4];
  __shared__ int wcnt[4];

  if (tid < GG) slab[tid] = gt_labels[b * GG + tid];
  for (int i = tid; i < BLKANCH; i += 256) ovrblk[i] = -1;

  #define PREFETCH(t, bufp)                                                  \
    do {                                                                     \
      const int a0_ = (t) * TILE;                                            \
      const int nch_ = (min(TILE, AA - a0_) * DD) >> 2;                      \
      const float* s_ = pred + ((size_t)b * AA + a0_) * DD;                  \
      _Pragma("unroll")                                                      \
      for (int j_ = 0; j_ < 6; ++j_) {                                       \
        int c_ = j_ * 256 + tid;                                             \
        if (c_ < nch_)                                                       \
          __builtin_amdgcn_global_load_lds(                                  \
              (glb_u32*)(s_ + c_ * 4), (lds_u32*)((bufp) + c_ * 4), 16, 0, 0);\
      }                                                                      \
    } while (0)

  PREFETCH(t0, &bufs[0][0]);
  __syncthreads();   // ovrblk/slab init visible; prologue tile resident

  // forced-match override scatter (max g == ascending last-write-wins)
  if (tid < GG && tid < gt_counts[b]) {
    int p = bestp[b * GG + tid];
    if (p >= abase && p < abase + BLKANCH) atomicMax(&ovrblk[p - abase], tid);
  }
  __syncthreads();

  const int r = tid >> 2;
  const int sub = tid & 3;
  float acc = 0.0f;
  int poscnt = 0;
  int cur = 0;

  for (int t = t0; t < t1; ++t) {
    if (t + 1 < t1) {
      PREFETCH(t + 1, &bufs[cur ^ 1][0]);
      __builtin_amdgcn_sched_barrier(0);   // keep issue ahead of compute
    }

    const int a0 = t * TILE;
    const int nr = min(TILE, AA - a0);
    const float* rows = &bufs[cur][0];

    if (r < nr) {
      const int a = a0 + r;
      int m = match[b * AA + a];
      { int o = ovrblk[a - abase]; if (o >= 0) m = o; }

      const float* row = rows + r * DD + 4;
      float v[21];
      float mx = -INFINITY;
      #pragma unroll
      for (int k = 0; k < 21; ++k) {
        const int cc = 4 * k + sub;
        float x = (cc < CC) ? row[cc] : -INFINITY;
        v[k] = x;
        mx = fmaxf(mx, x);
      }
      #pragma unroll
      for (int msk = 1; msk <= 2; msk <<= 1)
        mx = fmaxf(mx, __shfl_xor(mx, msk));
      float s = 0.0f;
      #pragma unroll
      for (int k = 0; k < 21; ++k) s += __expf(v[k] - mx);  // exp(-inf)=0 pads
      #pragma unroll
      for (int msk = 1; msk <= 2; msk <<= 1) s += __shfl_xor(s, msk);
      const float lse = mx + __logf(s);

      if (sub == 0) {
        if (m >= 0) {
          poscnt += 1;
          const int tgt = slab[m] + 1;
          float cls_ce = lse - row[tgt];
          float4 an = reinterpret_cast<const float4*>(anchors)[a];
          float4 gb = reinterpret_cast<const float4*>(gt_boxes)[b * GG + m];
          float tx = (gb.x - an.x) / an.z;
          float ty = (gb.y - an.y) / an.w;
          float tw = __logf(gb.z) - __logf(an.z);
          float th = __logf(gb.w) - __logf(an.w);
          acc += smoothl1(rows[r * DD + 0] - tx)
               + smoothl1(rows[r * DD + 1] - ty)
               + smoothl1(rows[r * DD + 2] - tw)
               + smoothl1(rows[r * DD + 3] - th)
               + cls_ce;
          all_neg[b * AA + a] = 0.0f;
        } else {
          float ce = lse - row[0];          // tgt==0 for negatives
          all_neg[b * AA + a] = fmaxf(ce, 0.0f);
        }
      }
    }

    __syncthreads();   // reads done + prefetch drained
    cur ^= 1;
  }

  #pragma unroll
  for (int msk = 1; msk < 64; msk <<= 1) {
    acc    += __shfl_xor(acc, msk);
    poscnt += __shfl_xor(poscnt, msk);
  }
  if ((tid & 63) == 0) {
    wsum[tid >> 6] = acc;
    wcnt[tid >> 6] = poscnt;
  }
  __syncthreads();
  if (tid == 0) {
    partials[b * NTB + blockIdx.x] = (wsum[0] + wsum[1]) + (wsum[2] + wsum[3]);
    int c = wcnt[0] + wcnt[1] + wcnt[2] + wcnt[3];
    if (c) atomicAdd(&n_pos[b], c);        // integer add: order-independent
  }
  #undef PREFETCH
}

// ---- per-batch top-K sum via radix select; last block also writes out[0].
// 1024 threads, 64 blocks. Parallel suffix-scan replaces the serial bin scan.
__global__ __launch_bounds__(1024) void k_select(
    const float* __restrict__ all_neg, const float* __restrict__ partials,
    const int* __restrict__ n_pos, float* __restrict__ batch_total,
    int* __restrict__ done_sel, float* __restrict__ out)
{
  const int b = blockIdx.x;
  const int tid = threadIdx.x;
  __shared__ unsigned u[AA];           // 34928 B
  __shared__ int hist16[16][257];      // 16448 B per-wave histograms
  __shared__ int hist[256];
  __shared__ unsigned sh_pref;
  __shared__ int sh_k;
  __shared__ int sflag;
  __shared__ float wf[16];
  __shared__ int wc[16];

  {
    const float* srcg = all_neg + (size_t)b * AA;   // 16B-aligned
    #pragma unroll
    for (int j = 0; j < 3; ++j) {
      int c = j * 1024 + tid;
      if (c < 2183)
        __builtin_amdgcn_global_load_lds(
            (glb_u32*)(srcg + c * 4), (lds_u32*)((float*)u + c * 4), 16, 0, 0);
    }
  }

  // wave-parallel partials sum (overlaps staging)
  float ps = 0.0f;
  if (tid < 16) {
    float pv = (tid < NTB) ? partials[b * NTB + tid] : 0.0f;
    #pragma unroll
    for (int m = 1; m < 16; m <<= 1) pv += __shfl_xor(pv, m);
    ps = pv;   // all 16 lanes hold the sum; tid 0 uses it
  }
  __syncthreads();

  const int np = n_pos[b];
  const int K = min(3 * np, AA - 1);
  const int wvid = tid >> 6;

  unsigned prefix = 0;
  int kk = K;
  for (int shift = 24; shift >= 0; shift -= 8) {
    int* hflat = &hist16[0][0];
    for (int i = tid; i < 16 * 257; i += 1024) hflat[i] = 0;
    __syncthreads();
    const unsigned hmask = (shift == 24) ? 0u : (0xFFFFFFFFu << (shift + 8));
    for (int i = tid; i < AA; i += 1024) {
      unsigned x = u[i];
      if ((x & hmask) == prefix)
        atomicAdd(&hist16[wvid][(x >> shift) & 255], 1);
    }
    __syncthreads();
    if (tid < 256) {
      int s = 0;
      #pragma unroll
      for (int h = 0; h < 16; ++h) s += hist16[h][tid];
      hist[tid] = s;
    }
    __syncthreads();
    // parallel suffix scan: hist[bin] <- sum_{j>=bin} hist[j]
    #pragma unroll
    for (int off = 1; off < 256; off <<= 1) {
      int v = 0;
      if (tid < 256) v = hist[tid] + ((tid + off < 256) ? hist[tid + off] : 0);
      __syncthreads();
      if (tid < 256) hist[tid] = v;
      __syncthreads();
    }
    if (tid < 256) {
      int s_here = hist[tid];
      int s_next = (tid < 255) ? hist[tid + 1] : 0;
      if (s_here >= kk && s_next < kk) {       // exactly one bin satisfies
        sh_pref = prefix | ((unsigned)tid << shift);
        sh_k = kk - s_next;
      }
    }
    __syncthreads();
    prefix = sh_pref;
    kk = sh_k;
    __syncthreads();
  }
  const float tstar = __uint_as_float(prefix);   // exact K-th largest

  float ssum = 0.0f; int cgt = 0;
  for (int i = tid; i < AA; i += 1024) {
    float x = __uint_as_float(u[i]);
    if (x > tstar) { ssum += x; cgt += 1; }
  }
  #pragma unroll
  for (int m = 1; m < 64; m <<= 1) {
    ssum += __shfl_xor(ssum, m);
    cgt  += __shfl_xor(cgt, m);
  }
  if ((tid & 63) == 0) { wf[wvid] = ssum; wc[wvid] = cgt; }
  __syncthreads();
  if (tid == 0) {
    float S = 0.0f; int Cg = 0;
    #pragma unroll
    for (int w = 0; w < 16; ++w) { S += wf[w]; Cg += wc[w]; }
    float neg_sum = S + (float)(K - Cg) * tstar;
    batch_total[b] = (ps + neg_sum) / (float)np;
    __threadfence();                       // release (only 4B dirty: cheap)
    int old = atomicAdd(done_sel, 1);
    sflag = (old == BB - 1) ? 1 : 0;
  }
  __syncthreads();

  if (sflag) {                             // last finishing block: final sum
    __threadfence();                       // acquire
    if (tid < 64) {
      float v = batch_total[tid];
      #pragma unroll
      for (int m = 1; m < 64; m <<= 1) v += __shfl_xor(v, m);
      if (tid == 0) out[0] = v;
    }
  }
}

extern "C" void kernel_launch(void* const* d_in, const int* in_sizes, int n_in,
                              void* d_out, int out_size, void* d_ws, size_t ws_size,
                              hipStream_t stream) {
  (void)in_sizes; (void)n_in; (void)out_size; (void)ws_size;
  const float* pred      = (const float*)d_in[0];
  const float* anchors   = (const float*)d_in[1];
  const float* gt_boxes  = (const float*)d_in[2];
  const int*   gt_labels = (const int*)d_in[3];
  const int*   gt_counts = (const int*)d_in[4];

  char* ws = (char*)d_ws;
  int*   match       = (int*)(ws + 0);
  float* all_neg     = (float*)(ws + 2235392);
  float* partials    = (float*)(ws + 4470784);
  float* batch_total = (float*)(ws + 4473856);
  int*   bestp       = (int*)(ws + 4474112);
  int*   n_pos       = (int*)(ws + 4482304);
  int*   done_sel    = (int*)(ws + 4482560);
  float* out = (float*)d_out;

  hipLaunchKernelGGL(k_match, dim3(NAB + GG, BB), dim3(256), 0, stream,
                     anchors, gt_boxes, gt_counts, match, bestp, n_pos, done_sel);
  hipLaunchKernelGGL(k_loss, dim3(NTB, BB), dim3(256), 0, stream,
                     pred, anchors, gt_boxes, gt_labels, gt_counts, match, bestp,
                     all_neg, partials, n_pos);
  hipLaunchKernelGGL(k_select, dim3(BB), dim3(1024), 0, stream,
                     all_neg, partials, n_pos, batch_total, done_sel, out);
}